// Round 1
// baseline (776.152 us; speedup 1.0000x reference)
//
#include <hip/hip_runtime.h>

#define NODES 100000
#define EDGES 1600000
#define FEATS 128
#define NCLS  16

typedef unsigned int  u32;
typedef unsigned short u16;
typedef __attribute__((ext_vector_type(8))) short short8;
typedef __attribute__((ext_vector_type(4))) float f32x4;

__device__ __forceinline__ float b2f(u16 v){ return __uint_as_float(((u32)v)<<16); }
__device__ __forceinline__ u16 f2b(float f){
  u32 u = __float_as_uint(f);
  u += 0x7fffu + ((u>>16)&1u);   // RNE
  return (u16)(u>>16);
}
__device__ __forceinline__ float blo(u32 p){ return __uint_as_float(p<<16); }
__device__ __forceinline__ float bhi(u32 p){ return __uint_as_float(p & 0xffff0000u); }

// ---------------- graph build ----------------

__global__ void deg_hist_k(const int* __restrict__ dst, int* __restrict__ deg, int E){
  int i = blockIdx.x*256 + threadIdx.x;
  if (i < E) atomicAdd(&deg[dst[i]], 1);
}

// block scans 2048 elems (256 thr x 8); writes local exclusive scan + block sum
__global__ __launch_bounds__(256) void scan1_k(const int* __restrict__ in, int* __restrict__ out,
                                               int* __restrict__ bsum, int n){
  __shared__ int sh[256];
  int t = threadIdx.x;
  int base = blockIdx.x*2048 + t*8;
  int v[8]; int s = 0;
  #pragma unroll
  for (int j=0;j<8;++j) v[j] = (base+j < n) ? in[base+j] : 0;
  #pragma unroll
  for (int j=0;j<8;++j){ int tmp = v[j]; v[j] = s; s += tmp; }
  sh[t] = s; __syncthreads();
  for (int off=1; off<256; off<<=1){
    int x = (t>=off) ? sh[t-off] : 0;
    __syncthreads();
    sh[t] += x;
    __syncthreads();
  }
  int excl = sh[t] - s;
  #pragma unroll
  for (int j=0;j<8;++j) if (base+j < n) out[base+j] = excl + v[j];
  if (t == 255) bsum[blockIdx.x] = sh[255];
}

__global__ void scan2_k(const int* __restrict__ bsum, int* __restrict__ boff, int nb){
  int lane = threadIdx.x;           // 64 threads, single wave
  int orig = (lane < nb) ? bsum[lane] : 0;
  int v = orig;
  for (int off=1; off<64; off<<=1){
    int x = __shfl_up(v, off);
    if (lane >= off) v += x;
  }
  if (lane < nb) boff[lane] = v - orig;
}

__global__ void scan3_k(int* __restrict__ offs, const int* __restrict__ boff,
                        int* __restrict__ cur, int n){
  int i = blockIdx.x*256 + threadIdx.x;
  if (i < n){
    int v = offs[i] + boff[i>>11];
    offs[i] = v;
    if (i < n-1) cur[i] = v;
  }
}

__global__ void scatter_k(const int* __restrict__ src, const int* __restrict__ dst,
                          int* __restrict__ cur, int* __restrict__ esrc, int E){
  int i = blockIdx.x*256 + threadIdx.x;
  if (i < E){
    int p = atomicAdd(&cur[dst[i]], 1);
    esrc[p] = src[i];
  }
}

// ---------------- dtype conversion ----------------

__global__ void convf_k(const float* __restrict__ in, u16* __restrict__ o, int n4){
  int i = blockIdx.x*256 + threadIdx.x;
  if (i < n4){
    float4 x = ((const float4*)in)[i];
    ushort4 r;
    r.x = f2b(x.x); r.y = f2b(x.y); r.z = f2b(x.z); r.w = f2b(x.w);
    ((ushort4*)o)[i] = r;
  }
}

// W[K][N] row-major -> Wt[N][K] bf16
__global__ void convw_k(const float* __restrict__ W, u16* __restrict__ Wt, int Kd, int Nd){
  int i = blockIdx.x*256 + threadIdx.x;
  if (i < Kd*Nd){
    int k = i / Nd, nn = i - k*Nd;
    Wt[nn*Kd + k] = f2b(W[i]);
  }
}

// ---------------- GEMM: y[M x N] = h[M x 128] * W  (Wt is [N][128] bf16) ----------------
// 16x16x32 bf16 MFMA. Block = 4 waves x 16 rows = 64 rows; each wave does NT col-tiles.

template<int NT>
__global__ __launch_bounds__(256) void gemm_k(const u16* __restrict__ h,
                                              const u16* __restrict__ Wt,
                                              u16* __restrict__ y, int M){
  const int K = FEATS;
  const int N = NT*16;
  int lane = threadIdx.x & 63;
  int wave = threadIdx.x >> 6;
  int m    = lane & 15;
  int quad = lane >> 4;
  int row0 = (blockIdx.x*4 + wave)*16;
  if (row0 >= M) return;
  int rowA = row0 + m; if (rowA > M-1) rowA = M-1;
  const u16* pa = h + (size_t)rowA*K + quad*8;

  f32x4 acc[NT];
  #pragma unroll
  for (int j=0;j<NT;++j) acc[j] = (f32x4){0.f,0.f,0.f,0.f};

  #pragma unroll
  for (int kk=0; kk<K; kk+=32){
    short8 a = *(const short8*)(pa + kk);
    #pragma unroll
    for (int j=0;j<NT;++j){
      short8 b = *(const short8*)(Wt + (size_t)(j*16 + m)*K + kk + quad*8);
      acc[j] = __builtin_amdgcn_mfma_f32_16x16x32_bf16(a, b, acc[j], 0, 0, 0);
    }
  }

  #pragma unroll
  for (int j=0;j<NT;++j){
    #pragma unroll
    for (int r=0;r<4;++r){
      int row = row0 + quad*4 + r;                  // C/D: row = quad*4 + reg
      if (row < M) y[(size_t)row*N + j*16 + m] = f2b(acc[j][r]);  // col = lane&15
    }
  }
}

// ---------------- aggregation epilogue, 128 feats ----------------
// one wave per node; lane covers a bf16 pair; out = relu((1+eps)*y[v] + inv_deg*sum y[src] + b)

__global__ __launch_bounds__(256) void agg128_k(const u32* __restrict__ y2,
    const int* __restrict__ offs, const int* __restrict__ esrc,
    const float* __restrict__ bias, const float* __restrict__ epsv, int ei,
    u32* __restrict__ hout, int M){
  int lane = threadIdx.x & 63;
  int wid  = blockIdx.x*4 + (threadIdx.x >> 6);
  if (wid >= M) return;
  int start = offs[wid], end = offs[wid+1];
  float inv = 1.f / fmaxf((float)(end - start), 1.f);
  float e1  = 1.f + epsv[ei];
  float a0 = 0.f, a1 = 0.f;
  for (int base = start; base < end; base += 64){
    int nn = end - base; if (nn > 64) nn = 64;
    int my = 0;
    if (base + lane < end) my = esrc[base + lane];
    for (int j = 0; j < nn; ++j){
      int s = __shfl(my, j);
      u32 p = y2[(size_t)s*64 + lane];
      a0 += blo(p); a1 += bhi(p);
    }
  }
  u32 pv = y2[(size_t)wid*64 + lane];
  float o0 = e1*blo(pv) + inv*a0 + bias[lane*2];
  float o1 = e1*bhi(pv) + inv*a1 + bias[lane*2+1];
  o0 = fmaxf(o0, 0.f); o1 = fmaxf(o1, 0.f);
  hout[(size_t)wid*64 + lane] = (u32)f2b(o0) | ((u32)f2b(o1) << 16);
}

// ---------------- final layer aggregation, 16 feats, f32 out, no relu ----------------

__global__ void agg16_k(const u16* __restrict__ y,
    const int* __restrict__ offs, const int* __restrict__ esrc,
    const float* __restrict__ bias, const float* __restrict__ epsv,
    float* __restrict__ out, int M){
  int t = blockIdx.x*256 + threadIdx.x;
  if (t >= M*16) return;
  int v = t >> 4, f = t & 15;
  int start = offs[v], end = offs[v+1];
  float inv = 1.f / fmaxf((float)(end - start), 1.f);
  float e1  = 1.f + epsv[3];
  float acc = 0.f;
  for (int e = start; e < end; ++e){
    int s = esrc[e];
    acc += b2f(y[(size_t)s*16 + f]);
  }
  out[t] = e1*b2f(y[(size_t)v*16 + f]) + inv*acc + bias[f];
}

// ---------------- launch ----------------

extern "C" void kernel_launch(void* const* d_in, const int* in_sizes, int n_in,
                              void* d_out, int out_size, void* d_ws, size_t ws_size,
                              hipStream_t stream){
  const float* feats = (const float*)d_in[0];
  const int*   src   = (const int*)d_in[1];
  const int*   dst   = (const int*)d_in[2];
  const float* W0 = (const float*)d_in[3];  const float* b0 = (const float*)d_in[4];
  const float* W1 = (const float*)d_in[5];  const float* b1 = (const float*)d_in[6];
  const float* W2 = (const float*)d_in[7];  const float* b2 = (const float*)d_in[8];
  const float* W3 = (const float*)d_in[9];  const float* b3 = (const float*)d_in[10];
  const float* eps = (const float*)d_in[11];

  char* w = (char*)d_ws;
  auto alloc = [&](size_t bytes)->char*{
    char* p = w; w += (bytes + 255) & ~(size_t)255; return p;
  };
  int* deg  = (int*)alloc(sizeof(int)*(NODES+1));
  int* offs = (int*)alloc(sizeof(int)*(NODES+1));
  int* cur  = (int*)alloc(sizeof(int)*NODES);
  int* bsum = (int*)alloc(sizeof(int)*64);
  int* boff = (int*)alloc(sizeof(int)*64);
  int* esrc = (int*)alloc(sizeof(int)*EDGES);
  u16* hb   = (u16*)alloc(sizeof(u16)*(size_t)NODES*FEATS);
  u16* yb   = (u16*)alloc(sizeof(u16)*(size_t)NODES*FEATS);
  u16* Wt0  = (u16*)alloc(sizeof(u16)*128*128);
  u16* Wt1  = (u16*)alloc(sizeof(u16)*128*128);
  u16* Wt2  = (u16*)alloc(sizeof(u16)*128*128);
  u16* Wt3  = (u16*)alloc(sizeof(u16)*16*128);

  // ---- CSR build ----
  hipMemsetAsync(deg, 0, sizeof(int)*(NODES+1), stream);
  deg_hist_k<<<(EDGES+255)/256, 256, 0, stream>>>(dst, deg, EDGES);
  int nscan = NODES + 1;
  int nb = (nscan + 2047)/2048;   // 49
  scan1_k<<<nb, 256, 0, stream>>>(deg, offs, bsum, nscan);
  scan2_k<<<1, 64, 0, stream>>>(bsum, boff, nb);
  scan3_k<<<(nscan+255)/256, 256, 0, stream>>>(offs, boff, cur, nscan);
  scatter_k<<<(EDGES+255)/256, 256, 0, stream>>>(src, dst, cur, esrc, EDGES);

  // ---- convert inputs to bf16 ----
  convf_k<<<((NODES*FEATS/4)+255)/256, 256, 0, stream>>>(feats, hb, NODES*FEATS/4);
  convw_k<<<(128*128+255)/256, 256, 0, stream>>>(W0, Wt0, 128, 128);
  convw_k<<<(128*128+255)/256, 256, 0, stream>>>(W1, Wt1, 128, 128);
  convw_k<<<(128*128+255)/256, 256, 0, stream>>>(W2, Wt2, 128, 128);
  convw_k<<<(128*16 +255)/256, 256, 0, stream>>>(W3, Wt3, 128, 16);

  int gblocks = (NODES + 63)/64;
  int ablocks = (NODES + 3)/4;

  // layer 0..2: y = h@W ; h = relu((1+eps)y + mean_agg(y) + b)
  gemm_k<8><<<gblocks, 256, 0, stream>>>(hb, Wt0, yb, NODES);
  agg128_k<<<ablocks, 256, 0, stream>>>((const u32*)yb, offs, esrc, b0, eps, 0, (u32*)hb, NODES);
  gemm_k<8><<<gblocks, 256, 0, stream>>>(hb, Wt1, yb, NODES);
  agg128_k<<<ablocks, 256, 0, stream>>>((const u32*)yb, offs, esrc, b1, eps, 1, (u32*)hb, NODES);
  gemm_k<8><<<gblocks, 256, 0, stream>>>(hb, Wt2, yb, NODES);
  agg128_k<<<ablocks, 256, 0, stream>>>((const u32*)yb, offs, esrc, b2, eps, 2, (u32*)hb, NODES);

  // layer 3: y = h@W3 (N=16); out = (1+eps)y + mean_agg(y) + b  (f32, no relu)
  gemm_k<1><<<gblocks, 256, 0, stream>>>(hb, Wt3, yb, NODES);
  agg16_k<<<((NODES*16)+255)/256, 256, 0, stream>>>(yb, offs, esrc, b3, eps, (float*)d_out, NODES);
}